// Round 11
// baseline (231.904 us; speedup 1.0000x reference)
//
#include <hip/hip_runtime.h>
#include <hip/hip_bf16.h>
#include <math.h>

#define B_   256
#define D1_  512
#define T_   256
#define O1_  256
#define O2_  128
#define OT   64

typedef __attribute__((ext_vector_type(8))) _Float16 f16x8;
typedef __attribute__((ext_vector_type(4))) float f32x4;

// 8 floats -> fp16x8 (hi only)
__device__ inline f16x8 cvt8h(const float* v) {
    f16x8 r;
    #pragma unroll
    for (int j = 0; j < 8; ++j) r[j] = (_Float16)v[j];
    return r;
}
// 8 floats -> hi + lo fp16x8 (hi = rne(v), lo = rne(v - hi))
__device__ inline void split8(const float* v, f16x8& h, f16x8& l) {
    #pragma unroll
    for (int j = 0; j < 8; ++j) {
        _Float16 hh = (_Float16)v[j];
        h[j] = hh;
        l[j] = (_Float16)(v[j] - (float)hh);
    }
}
__device__ inline f16x8 ldb128(const char* p) { return *(const f16x8*)p; }

#define MFMAH __builtin_amdgcn_mfma_f32_16x16x32_f16

// OT=64 o-rows per block, 1024 threads (16 waves: 2m x 8n), LDS = 36 KB ->
// 2 blocks/CU (32 waves/CU = max occupancy). NO operand staging in LDS:
// B-fragments (x / W / W2) load DIRECTLY from global per-lane (lane16 = n,
// k = lg*8+j, 64B-coalesced segments; W/W2 are L2-resident). Only 3 barriers
// in the whole kernel (Eh publish, softmax reduce, blend publish).
__global__ __launch_bounds__(1024) void tabl_mfma(
    const float* __restrict__ x, const float* __restrict__ W1,
    const float* __restrict__ W, const float* __restrict__ W2,
    const float* __restrict__ alpha, const float* __restrict__ bias,
    float* __restrict__ out)
{
    __shared__ __align__(16) char Eh[OT * 512];   // E-hi / blended-hi, XOR-swizzled rows
    __shared__ float redm[8][OT];
    __shared__ float reds[8][OT];

    const int tid    = threadIdx.x;
    const int lane16 = tid & 15;
    const int lg     = (tid >> 4) & 3;
    const int wid    = tid >> 6;     // 0..15
    const int wm     = wid >> 3;     // 0..1  (row half)
    const int wn     = wid & 7;      // 0..7  (col group)

    // XCD swizzle: the 4 o-tiles of a batch land on the same XCD.
    const int bi = blockIdx.x;
    const int wg = (bi & 7) * 128 + (bi >> 3);
    const int b     = wg >> 2;
    const int obase = (wg & 3) * OT;

    const int eR[2]    = { wm * 32 + lane16, wm * 32 + 16 + lane16 };
    const int eBase[2] = { eR[0] * 512, eR[1] * 512 };
    const int eSw[2]   = { (eR[0] & 7) << 4, (eR[1] & 7) << 4 };

    // ================= Stage 1: E = W1h @ (xh + xl)  (2-term fp16) =================
    f32x4 Eacc[2][2];
    #pragma unroll
    for (int mt = 0; mt < 2; ++mt)
        #pragma unroll
        for (int nt = 0; nt < 2; ++nt) Eacc[mt][nt] = (f32x4){0.f,0.f,0.f,0.f};

    const float* a0  = W1 + (size_t)(obase + eR[0]) * D1_ + lg * 8;
    const float* a1  = W1 + (size_t)(obase + eR[1]) * D1_ + lg * 8;
    const float* xb0 = x + (size_t)b * (D1_ * T_) + (wn * 32 + lane16) + (size_t)lg * 8 * T_;
    const float* xb1 = xb0 + 16;

    #pragma unroll 2
    for (int c = 0; c < 16; ++c) {
        // A fragments: W1 rows, k contiguous (hi only)
        float av[8];
        f16x8 Ah[2];
        *(float4*)&av[0] = *(const float4*)(a0 + c * 32);
        *(float4*)&av[4] = *(const float4*)(a0 + c * 32 + 4);
        Ah[0] = cvt8h(av);
        *(float4*)&av[0] = *(const float4*)(a1 + c * 32);
        *(float4*)&av[4] = *(const float4*)(a1 + c * 32 + 4);
        Ah[1] = cvt8h(av);
        // B fragments direct from global: x[k][t], k = c*32 + lg*8 + j
        #pragma unroll
        for (int nt = 0; nt < 2; ++nt) {
            const float* xp = (nt ? xb1 : xb0) + (size_t)c * 32 * T_;
            float xv[8];
            #pragma unroll
            for (int j = 0; j < 8; ++j) xv[j] = xp[(size_t)j * T_];
            f16x8 Bh, Bl;
            split8(xv, Bh, Bl);
            #pragma unroll
            for (int mt = 0; mt < 2; ++mt) {
                Eacc[mt][nt] = MFMAH(Ah[mt], Bh, Eacc[mt][nt], 0,0,0);
                Eacc[mt][nt] = MFMAH(Ah[mt], Bl, Eacc[mt][nt], 0,0,0);
            }
        }
    }

    // publish E-hi (fp16) to LDS (XOR-swizzled); Eacc dies here (no spills)
    #pragma unroll
    for (int mt = 0; mt < 2; ++mt)
        #pragma unroll
        for (int nt = 0; nt < 2; ++nt)
            #pragma unroll
            for (int i = 0; i < 4; ++i) {
                int r = wm * 32 + mt * 16 + lg * 4 + i;
                int t = wn * 32 + nt * 16 + lane16;
                union { _Float16 h; unsigned short u; } cc;
                cc.h = (_Float16)Eacc[mt][nt][i];
                *(unsigned short*)(Eh + r * 512 + ((2 * t) ^ ((r & 7) << 4))) = cc.u;
            }
    __syncthreads();   // barrier 1

    // ================= Stage 2: S = Eh @ Wh  (fp16 hi-only) =================
    f32x4 Sacc[2][2];
    #pragma unroll
    for (int mt = 0; mt < 2; ++mt)
        #pragma unroll
        for (int nt = 0; nt < 2; ++nt) Sacc[mt][nt] = (f32x4){0.f,0.f,0.f,0.f};

    const float* wb0 = W + (wn * 32 + lane16) + (size_t)lg * 8 * T_;
    const float* wb1 = wb0 + 16;

    #pragma unroll 2
    for (int c = 0; c < 8; ++c) {
        f16x8 Af[2];
        #pragma unroll
        for (int mt = 0; mt < 2; ++mt)
            Af[mt] = ldb128(Eh + eBase[mt] + ((c * 64 + lg * 16) ^ eSw[mt]));
        #pragma unroll
        for (int nt = 0; nt < 2; ++nt) {
            const float* wp = (nt ? wb1 : wb0) + (size_t)c * 32 * T_;
            float wv[8];
            #pragma unroll
            for (int j = 0; j < 8; ++j) wv[j] = wp[(size_t)j * T_];
            f16x8 Bf = cvt8h(wv);
            #pragma unroll
            for (int mt = 0; mt < 2; ++mt)
                Sacc[mt][nt] = MFMAH(Af[mt], Bf, Sacc[mt][nt], 0,0,0);
        }
    }

    // ============ row softmax over s (8 wn groups) + blend (from Eh) ============
    const float a_ = alpha[0];
    float pm[2][4];
    #pragma unroll
    for (int mt = 0; mt < 2; ++mt)
        #pragma unroll
        for (int i = 0; i < 4; ++i) {
            float m = fmaxf(Sacc[mt][0][i], Sacc[mt][1][i]);
            m = fmaxf(m, __shfl_xor(m, 1));
            m = fmaxf(m, __shfl_xor(m, 2));
            m = fmaxf(m, __shfl_xor(m, 4));
            m = fmaxf(m, __shfl_xor(m, 8));
            float p0 = __expf(Sacc[mt][0][i] - m);
            float p1 = __expf(Sacc[mt][1][i] - m);
            Sacc[mt][0][i] = p0; Sacc[mt][1][i] = p1;
            float s = p0 + p1;
            s += __shfl_xor(s, 1);
            s += __shfl_xor(s, 2);
            s += __shfl_xor(s, 4);
            s += __shfl_xor(s, 8);
            pm[mt][i] = m;
            if (lane16 == 0) {
                int r = wm * 32 + mt * 16 + lg * 4 + i;
                redm[wn][r] = m; reds[wn][r] = s;
            }
        }
    __syncthreads();   // barrier 2 (also: all stage-2 Eh reads done)

    #pragma unroll
    for (int mt = 0; mt < 2; ++mt)
        #pragma unroll
        for (int i = 0; i < 4; ++i) {
            int r = wm * 32 + mt * 16 + lg * 4 + i;
            float M = redm[0][r];
            #pragma unroll
            for (int g = 1; g < 8; ++g) M = fmaxf(M, redm[g][r]);
            float den = 0.f;
            #pragma unroll
            for (int g = 0; g < 8; ++g) den += reds[g][r] * __expf(redm[g][r] - M);
            float sc = __expf(pm[mt][i] - M) / den;
            #pragma unroll
            for (int nt = 0; nt < 2; ++nt) {
                float f = a_ + (1.f - a_) * Sacc[mt][nt][i] * sc;
                int t = wn * 32 + nt * 16 + lane16;
                int off = r * 512 + ((2 * t) ^ ((r & 7) << 4));
                union { _Float16 h; unsigned short u; } cc;
                cc.u = *(const unsigned short*)(Eh + off);
                float v = (float)cc.h * f;
                cc.h = (_Float16)v;
                *(unsigned short*)(Eh + off) = cc.u;
            }
        }
    __syncthreads();   // barrier 3

    // ========== Stage 3: Y = blended_h @ W2h + bias (fp16 hi-only) ==========
    f32x4 Yacc[2];
    Yacc[0] = (f32x4){0.f,0.f,0.f,0.f};
    Yacc[1] = (f32x4){0.f,0.f,0.f,0.f};

    const float* zb = W2 + (wn * 16 + lane16) + (size_t)lg * 8 * O2_;

    #pragma unroll 2
    for (int c = 0; c < 8; ++c) {
        f16x8 Af[2];
        #pragma unroll
        for (int mt = 0; mt < 2; ++mt)
            Af[mt] = ldb128(Eh + eBase[mt] + ((c * 64 + lg * 16) ^ eSw[mt]));
        float zv[8];
        #pragma unroll
        for (int j = 0; j < 8; ++j) zv[j] = zb[(size_t)(c * 32 + j) * O2_];
        f16x8 Bf = cvt8h(zv);
        #pragma unroll
        for (int mt = 0; mt < 2; ++mt)
            Yacc[mt] = MFMAH(Af[mt], Bf, Yacc[mt], 0,0,0);
    }

    // epilogue: + bias, store pre-softmax Y
    #pragma unroll
    for (int mt = 0; mt < 2; ++mt)
        #pragma unroll
        for (int i = 0; i < 4; ++i) {
            int o  = obase + wm * 32 + mt * 16 + lg * 4 + i;
            int s2 = wn * 16 + lane16;
            out[((size_t)b * O1_ + o) * O2_ + s2] = Yacc[mt][i] + bias[(size_t)o * O2_ + s2];
        }
}

// in-place softmax over axis 1 (O1); one block per batch
__global__ __launch_bounds__(256) void softmax_o1(float* __restrict__ out)
{
    __shared__ float sm[2][128], ss[2][128];
    const int b  = blockIdx.x;
    const int s2 = threadIdx.x & 127;
    const int oh = threadIdx.x >> 7;
    float* p = out + (size_t)b * (O1_ * O2_) + s2;
    float m = -INFINITY, s = 0.f;
    #pragma unroll 4
    for (int o = oh * 128; o < oh * 128 + 128; ++o) {
        float v = p[(size_t)o * O2_];
        float mn = fmaxf(m, v);
        s = s * __expf(m - mn) + __expf(v - mn);
        m = mn;
    }
    sm[oh][s2] = m; ss[oh][s2] = s;
    __syncthreads();
    float M = fmaxf(sm[0][s2], sm[1][s2]);
    float S = ss[0][s2] * __expf(sm[0][s2] - M) + ss[1][s2] * __expf(sm[1][s2] - M);
    float inv = 1.f / S;
    #pragma unroll 4
    for (int o = oh * 128; o < oh * 128 + 128; ++o) {
        float v = p[(size_t)o * O2_];
        p[(size_t)o * O2_] = __expf(v - M) * inv;
    }
}

extern "C" void kernel_launch(void* const* d_in, const int* in_sizes, int n_in,
                              void* d_out, int out_size, void* d_ws, size_t ws_size,
                              hipStream_t stream)
{
    const float* x     = (const float*)d_in[0];
    const float* W1    = (const float*)d_in[1];
    const float* W     = (const float*)d_in[2];
    const float* W2    = (const float*)d_in[3];
    const float* alpha = (const float*)d_in[4];
    const float* bias  = (const float*)d_in[5];
    float* out = (float*)d_out;

    tabl_mfma<<<dim3(1024), 1024, 0, stream>>>(x, W1, W, W2, alpha, bias, out);
    softmax_o1<<<B_, 256, 0, stream>>>(out);
}